// Round 1
// baseline (18310.611 us; speedup 1.0000x reference)
//
#include <hip/hip_runtime.h>
#include <cstdint>
#include <cstddef>

typedef unsigned short u16;
typedef unsigned int u32;
typedef __attribute__((ext_vector_type(8))) short bf16x8;  // 8 bf16 (4 VGPRs) — MFMA A/B frag
typedef __attribute__((ext_vector_type(4))) float f32x4;   // MFMA C/D frag

#define T_SEQ 512
#define HID 512

// ---------- dtype helpers ----------
__device__ __forceinline__ u16 f2bf(float f) {
  union { float f; u32 i; } c; c.f = f;
  u32 r = (c.i + 0x7FFFu + ((c.i >> 16) & 1u)) >> 16;  // RNE
  return (u16)r;
}
__device__ __forceinline__ u16 f2h(float f) {
  union { _Float16 h; u16 u; } c; c.h = (_Float16)f; return c.u;
}
__device__ __forceinline__ float h2f(u16 u) {
  union { u16 u; _Float16 h; } c; c.u = u; return (float)c.h;
}
__device__ __forceinline__ float sigmf(float x) { return 1.f / (1.f + __expf(-x)); }
__device__ __forceinline__ float tanhfast(float x) {
  float e = __expf(2.f * x); return 1.f - 2.f / (e + 1.f);  // saturates to ±1
}
__device__ __forceinline__ bf16x8 pack8(const float* p) {
  float4 a = *(const float4*)(p);
  float4 b = *(const float4*)(p + 4);
  bf16x8 fr;
  fr[0] = (short)f2bf(a.x); fr[1] = (short)f2bf(a.y);
  fr[2] = (short)f2bf(a.z); fr[3] = (short)f2bf(a.w);
  fr[4] = (short)f2bf(b.x); fr[5] = (short)f2bf(b.y);
  fr[6] = (short)f2bf(b.z); fr[7] = (short)f2bf(b.w);
  return fr;
}

// ---------------------------------------------------------------------------
// xg GEMM: xg[dir][m][n] = sum_k A[m][k] * W[dir][n][k] + bias[dir][n]
// A: [8192, K] (fp32 if AF32 else bf16) row-major; W: [1536, K] fp32 row-major.
// out: fp16 [8192,1536]. 128x128 tile, BK=32, 4 waves (2x2), 4x4 16x16x32 MFMA.
// (unchanged from previous round — ~90 µs/dispatch, not the bottleneck)
// ---------------------------------------------------------------------------
template <int AF32>
__launch_bounds__(256)
__global__ void gemm_xg(const void* __restrict__ Av,
                        const float* __restrict__ W0, const float* __restrict__ W1,
                        const float* __restrict__ b0, const float* __restrict__ b1,
                        u16* __restrict__ xg0, u16* __restrict__ xg1, int K) {
  const int dir = blockIdx.z;
  const float* W = dir ? W1 : W0;
  const float* bias = dir ? b1 : b0;
  u16* xg = dir ? xg1 : xg0;
  const int bm = blockIdx.x, bn = blockIdx.y;
  const int tid = threadIdx.x, lane = tid & 63, wv = tid >> 6;
  const int wm = wv & 1, wn = wv >> 1, quad = lane >> 4, l15 = lane & 15;

  __shared__ u16 As[128 * 40];  // +8 pad per 32-elem row -> conflict-free b128 reads
  __shared__ u16 Bs[128 * 40];

  f32x4 acc[4][4] = {};
  const float* Wb = W + (size_t)(bn * 128) * K;

  for (int k0 = 0; k0 < K; k0 += 32) {
    __syncthreads();  // protect LDS from previous iter's readers
    if constexpr (AF32) {
      const float* Ab = (const float*)Av + (size_t)(bm * 128) * K;
#pragma unroll
      for (int it = 0; it < 4; ++it) {
        int c = tid + it * 256;  // 1024 float4 chunks
        int row = c >> 3, kp = (c & 7) * 4;
        float4 v = *(const float4*)(Ab + (size_t)row * K + k0 + kp);
        ushort4 s = { f2bf(v.x), f2bf(v.y), f2bf(v.z), f2bf(v.w) };
        *(ushort4*)(&As[row * 40 + kp]) = s;
      }
    } else {
      const u16* Ab = (const u16*)Av + (size_t)(bm * 128) * K;
#pragma unroll
      for (int it = 0; it < 2; ++it) {
        int c = tid + it * 256;  // 512 chunks of 8 bf16
        int row = c >> 2, kp = (c & 3) * 8;
        *(bf16x8*)(&As[row * 40 + kp]) = *(const bf16x8*)(Ab + (size_t)row * K + k0 + kp);
      }
    }
#pragma unroll
    for (int it = 0; it < 4; ++it) {  // W is always fp32
      int c = tid + it * 256;
      int row = c >> 3, kp = (c & 7) * 4;
      float4 v = *(const float4*)(Wb + (size_t)row * K + k0 + kp);
      ushort4 s = { f2bf(v.x), f2bf(v.y), f2bf(v.z), f2bf(v.w) };
      *(ushort4*)(&Bs[row * 40 + kp]) = s;
    }
    __syncthreads();
    bf16x8 af[4], bfv[4];
#pragma unroll
    for (int i = 0; i < 4; ++i) {
      af[i] = *(const bf16x8*)(&As[(wm * 64 + i * 16 + l15) * 40 + quad * 8]);
      bfv[i] = *(const bf16x8*)(&Bs[(wn * 64 + i * 16 + l15) * 40 + quad * 8]);
    }
#pragma unroll
    for (int mi = 0; mi < 4; ++mi)
#pragma unroll
      for (int ni = 0; ni < 4; ++ni)
        acc[mi][ni] = __builtin_amdgcn_mfma_f32_16x16x32_bf16(af[mi], bfv[ni], acc[mi][ni], 0, 0, 0);
  }

  // epilogue: + bias, store fp16
#pragma unroll
  for (int ni = 0; ni < 4; ++ni) {
    int n = bn * 128 + wn * 64 + ni * 16 + l15;
    float bv = bias[n];
#pragma unroll
    for (int mi = 0; mi < 4; ++mi) {
      int m0 = bm * 128 + wm * 64 + mi * 16 + quad * 4;
#pragma unroll
      for (int r = 0; r < 4; ++r)
        xg[(size_t)(m0 + r) * 1536 + n] = f2h(acc[mi][ni][r] + bv);
    }
  }
}

// ---------------------------------------------------------------------------
// Persistent GRU recurrence, v2: latency-optimized step loop.
// Grid: (4 WGs per direction) x (ndir), 512 threads (8 waves), 1 WG/CU.
// WG w owns hidden cols [w*128, w*128+128); wave wv owns the 16-col quad
// wv*16.. for ALL THREE gates (gate-aligned tiles) => the MFMA D fragment
// (m=quad*4+r=batch, n=l15=col) makes the gate combine lane-local:
//   - no glds LDS round-trip, no __syncthreads anywhere in the step loop
//   - hprev carried in 4 fp32 regs/lane (exact carry), bhh in 3 regs
//   - xg slice prefetched into 12 regs at step top (hidden under the poll)
// whh: r,z gate B-frags register-resident (128 VGPR); n-gate B-frags in
// wave-PRIVATE LDS (8 x 16KB = 128KB) to stay under the 256-VGPR cap.
// Sync: per-WAVE release flags (32 per dir) instead of a shared counter —
// no RMW serialization; readers poll all 32 with one per-lane agent-scope
// load + __all, then an agent acquire fence (invalidates L1/L2 so the plain
// h-fragment loads see the LLC copy; per-XCD L2s are NOT coherent, §6 G16).
// Parity safety: a wave's reads of parity P at step t precede (program
// order) its flag t+2; a WG enters step t+1 (writing P) only after all
// flags >= t+2, so no buffer still being read is overwritten.
// Output stores are issued AFTER the flag release — off the critical path.
// ---------------------------------------------------------------------------
__launch_bounds__(512, 2)
__global__ void gru_rec(const u16* __restrict__ xg_f, const u16* __restrict__ xg_b,
                        const float* __restrict__ whh_f, const float* __restrict__ whh_b,
                        const float* __restrict__ bhh_f, const float* __restrict__ bhh_b,
                        const float* __restrict__ h0_f, const float* __restrict__ h0_b,
                        void* __restrict__ outp, int out_stride, int out_f32,
                        u16* __restrict__ hbuf, int* __restrict__ counters, int Tn) {
  const int dir = blockIdx.y;
  const u16* xg   = dir ? xg_b  : xg_f;
  const float* whh = dir ? whh_b : whh_f;
  const float* bhh = dir ? bhh_b : bhh_f;
  const float* h0  = dir ? h0_b  : h0_f;
  const int w = blockIdx.x;                      // 0..3
  const int tid = threadIdx.x, lane = tid & 63, wv = tid >> 6;  // wv 0..7
  const int quad = lane >> 4, l15 = lane & 15;
  const int gcol = w * 128 + wv * 16 + l15;      // hidden unit this lane owns
  int* flg = counters + dir * 1024;              // 32 per-wave flags
  u16* hb0 = hbuf + (dir * 2 + 0) * (16 * 512);
  u16* hb1 = hbuf + (dir * 2 + 1) * (16 * 512);
  const int dir_off = dir * 512;

  __shared__ u16 nlds[8 * 8192];                 // 128 KB: per-wave n-gate whh frags

  // --- whh B-frags: rows g*512+gcol, k = kt*32 + quad*8 + j (HW layout m89/m120) ---
  bf16x8 bfr[2][16];
  {
    const float* wr = whh + (size_t)(0 * 512 + gcol) * 512 + quad * 8;
    const float* wz = whh + (size_t)(1 * 512 + gcol) * 512 + quad * 8;
    const float* wn = whh + (size_t)(2 * 512 + gcol) * 512 + quad * 8;
#pragma unroll
    for (int kt = 0; kt < 16; ++kt) {
      bfr[0][kt] = pack8(wr + kt * 32);
      bfr[1][kt] = pack8(wz + kt * 32);
      *(bf16x8*)(&nlds[wv * 8192 + kt * 512 + lane * 8]) = pack8(wn + kt * 32);  // wave-private
    }
  }
  const float bh0 = bhh[0 * 512 + gcol];
  const float bh1 = bhh[1 * 512 + gcol];
  const float bh2 = bhh[2 * 512 + gcol];

  // --- init h: fp32 regs (exact carry) + publish bf16 h0 slice to hb1 ---
  float hv[4];
#pragma unroll
  for (int r = 0; r < 4; ++r) hv[r] = h0[(quad * 4 + r) * 512 + gcol];
#pragma unroll
  for (int r = 0; r < 4; ++r) {
    u32 hb = (u32)f2bf(hv[r]);
    u32 pb = (u32)__shfl_xor((int)hb, 1, 64);
    if (!(lane & 1))
      __hip_atomic_store((u32*)(hb1 + (quad * 4 + r) * 512 + gcol), hb | (pb << 16),
                         __ATOMIC_RELAXED, __HIP_MEMORY_SCOPE_AGENT);
  }
  if (lane == 0)
    __hip_atomic_store(&flg[w * 8 + wv], 1, __ATOMIC_RELEASE, __HIP_MEMORY_SCOPE_AGENT);

  for (int t = 0; t < Tn; ++t) {
    const int te = dir ? (Tn - 1 - t) : t;

    // (a) xg slice for this lane's 4 batch rows -> 12 regs (hidden under poll)
    u16 xv[12];
    {
      const u16* xb = xg + (size_t)te * 1536 + gcol;
#pragma unroll
      for (int r = 0; r < 4; ++r)
#pragma unroll
        for (int g = 0; g < 3; ++g)
          xv[r * 3 + g] = xb[(size_t)(quad * 4 + r) * Tn * 1536 + g * 512];
    }

    // (b) wait until all 32 producer waves have published h for step t
    {
      const int target = t + 1;
      while (1) {
        int v = (lane < 32)
            ? __hip_atomic_load(&flg[lane], __ATOMIC_RELAXED, __HIP_MEMORY_SCOPE_AGENT)
            : 0x7fffffff;
        if (__all(v >= target)) break;
        __builtin_amdgcn_s_sleep(1);
      }
      __builtin_amdgcn_fence(__ATOMIC_ACQUIRE, "agent");  // L1/L2 inv before plain h loads
    }

    // (c) A-frags: full 16x512 bf16 h from exchange buffer (LLC-hot, 16KB/WG)
    const u16* hp = ((t & 1) ? hb0 : hb1) + l15 * 512 + quad * 8;
    bf16x8 afr[16];
#pragma unroll
    for (int kt = 0; kt < 16; ++kt) afr[kt] = *(const bf16x8*)(hp + kt * 32);

    // (d) MFMA: three independent 16-deep chains (r,z from regs; n from LDS)
    f32x4 accr = {0.f, 0.f, 0.f, 0.f}, accz = accr, accn = accr;
#pragma unroll
    for (int kt = 0; kt < 16; ++kt) {
      bf16x8 nf = *(const bf16x8*)(&nlds[wv * 8192 + kt * 512 + lane * 8]);
      accr = __builtin_amdgcn_mfma_f32_16x16x32_bf16(afr[kt], bfr[0][kt], accr, 0, 0, 0);
      accz = __builtin_amdgcn_mfma_f32_16x16x32_bf16(afr[kt], bfr[1][kt], accz, 0, 0, 0);
      accn = __builtin_amdgcn_mfma_f32_16x16x32_bf16(afr[kt], nf, accn, 0, 0, 0);
    }

    // (e) lane-local gate combine + fp32 h update
#pragma unroll
    for (int r = 0; r < 4; ++r) {
      float xr = h2f(xv[r * 3 + 0]);
      float xz = h2f(xv[r * 3 + 1]);
      float xn = h2f(xv[r * 3 + 2]);
      float rg = sigmf(xr + accr[r] + bh0);
      float zg = sigmf(xz + accz[r] + bh1);
      float ng = tanhfast(xn + rg * (accn[r] + bh2));
      hv[r] = (1.f - zg) * ng + zg * hv[r];
    }

    // (f) publish bf16 h (packed pairs via shfl; agent-scope stores)
    u16* hbw = (t & 1) ? hb1 : hb0;
    u32 opk[4];
#pragma unroll
    for (int r = 0; r < 4; ++r) {
      u32 hb = (u32)f2bf(hv[r]);
      u32 pb = (u32)__shfl_xor((int)hb, 1, 64);
      opk[r] = hb | (pb << 16);
      if (!(lane & 1))
        __hip_atomic_store((u32*)(hbw + (quad * 4 + r) * 512 + gcol), opk[r],
                           __ATOMIC_RELAXED, __HIP_MEMORY_SCOPE_AGENT);
    }
    // (g) release: wave-level flag (vmcnt drain covers this wave's stores only)
    if (lane == 0)
      __hip_atomic_store(&flg[w * 8 + wv], t + 2, __ATOMIC_RELEASE, __HIP_MEMORY_SCOPE_AGENT);

    // (h) sequence output — AFTER the release, off the critical path
    if (out_f32) {
#pragma unroll
      for (int r = 0; r < 4; ++r) {
        float pf = __shfl_xor(hv[r], 1, 64);
        if (!(lane & 1)) {
          float2 o = { hv[r], pf };
          *(float2*)((float*)outp + (size_t)((quad * 4 + r) * Tn + te) * out_stride + dir_off + gcol) = o;
        }
      }
    } else {
#pragma unroll
      for (int r = 0; r < 4; ++r)
        if (!(lane & 1))
          *(u32*)((u16*)outp + (size_t)((quad * 4 + r) * Tn + te) * out_stride + dir_off + gcol) = opk[r];
    }
  }
}

// ---------------------------------------------------------------------------
// Final FC: d_out[b] = sigmoid(out2[b, T-1, :] . fc_w + fc_b)   (all fp32)
// ---------------------------------------------------------------------------
__global__ void fc_kernel(const float* __restrict__ out2, const float* __restrict__ fc_w,
                          const float* __restrict__ fc_b, float* __restrict__ dst) {
  int b = blockIdx.x, lane = threadIdx.x;  // 64 threads
  const float* row = out2 + ((size_t)b * T_SEQ + (T_SEQ - 1)) * HID;
  float s = 0.f;
  for (int j = lane; j < HID; j += 64) s += row[j] * fc_w[j];
#pragma unroll
  for (int off = 32; off > 0; off >>= 1) s += __shfl_down(s, off, 64);
  if (lane == 0) dst[b] = sigmf(s + fc_b[0]);
}

// ---------------------------------------------------------------------------
// inputs (fp32): 0 x, 1 h1, 2 h2, [3..6]=l0f(wih,whh,bih,bhh), [7..10]=l0b,
// [11..14]=l1f, [15..18]=l1b, [19..22]=l2f, [23..26]=l2b, [27..30]=g2, 31 fc_w, 32 fc_b
// d_out (fp32): 16 sigmoid logits, then out2 [16,512,512].
// ws: xg0 fp16 (8192*1536) | xg1 fp16 | outb bf16 (8192*1024) | hbuf bf16 (4*8192)
//     | counters (8192 int)
// ---------------------------------------------------------------------------
extern "C" void kernel_launch(void* const* d_in, const int* in_sizes, int n_in,
                              void* d_out, int out_size, void* d_ws, size_t ws_size,
                              hipStream_t stream) {
  const float* x  = (const float*)d_in[0];
  const float* h1 = (const float*)d_in[1];
  const float* h2 = (const float*)d_in[2];
  auto P = [&](int i) { return (const float*)d_in[i]; };

  u16* xg0 = (u16*)d_ws;
  u16* xg1 = xg0 + (size_t)8192 * 1536;
  u16* outb = xg1 + (size_t)8192 * 1536;
  u16* hbuf = outb + (size_t)8192 * 1024;
  int* counters = (int*)(hbuf + 4 * 8192);
  float* out_f = (float*)d_out;
  float* out2 = out_f + 16;

  hipMemsetAsync(counters, 0, 8192 * sizeof(int), stream);

  // layer 0 (A = x fp32, K=2048)
  gemm_xg<1><<<dim3(64, 12, 2), 256, 0, stream>>>(x, P(3), P(7), P(5), P(9), xg0, xg1, 2048);
  gru_rec<<<dim3(4, 2), 512, 0, stream>>>(xg0, xg1, P(4), P(8), P(6), P(10),
                                          h1, h1 + 8192, outb, 1024, 0, hbuf, counters, T_SEQ);
  // layer 1 (A = outb bf16, K=1024)
  gemm_xg<0><<<dim3(64, 12, 2), 256, 0, stream>>>(outb, P(11), P(15), P(13), P(17), xg0, xg1, 1024);
  gru_rec<<<dim3(4, 2), 512, 0, stream>>>(xg0, xg1, P(12), P(16), P(14), P(18),
                                          h1 + 2 * 8192, h1 + 3 * 8192, outb, 1024, 0, hbuf,
                                          counters + 2048, T_SEQ);
  // layer 2 (K=1024)
  gemm_xg<0><<<dim3(64, 12, 2), 256, 0, stream>>>(outb, P(19), P(23), P(21), P(25), xg0, xg1, 1024);
  gru_rec<<<dim3(4, 2), 512, 0, stream>>>(xg0, xg1, P(20), P(24), P(22), P(26),
                                          h1 + 4 * 8192, h1 + 5 * 8192, outb, 1024, 0, hbuf,
                                          counters + 4096, T_SEQ);
  // g2 (unidirectional, K=1024) -> writes out2 region of d_out (fp32)
  gemm_xg<0><<<dim3(64, 12, 1), 256, 0, stream>>>(outb, P(27), P(27), P(29), P(29), xg0, xg1, 1024);
  gru_rec<<<dim3(4, 1), 512, 0, stream>>>(xg0, xg0, P(28), P(28), P(30), P(30),
                                          h2, h2, out2, 512, 1, hbuf, counters + 6144, T_SEQ);
  fc_kernel<<<16, 64, 0, stream>>>(out2, P(31), P(32), out_f);
}

// Round 3
// 15641.158 us; speedup vs baseline: 1.1707x; 1.1707x over previous
//
#include <hip/hip_runtime.h>
#include <cstdint>
#include <cstddef>

typedef unsigned short u16;
typedef unsigned int u32;
typedef __attribute__((ext_vector_type(8))) short bf16x8;  // 8 bf16 (4 VGPRs) — MFMA A/B frag
typedef __attribute__((ext_vector_type(4))) float f32x4;   // MFMA C/D frag

#define T_SEQ 512
#define HID 512

// ---------- dtype helpers ----------
__device__ __forceinline__ u16 f2bf(float f) {
  union { float f; u32 i; } c; c.f = f;
  u32 r = (c.i + 0x7FFFu + ((c.i >> 16) & 1u)) >> 16;  // RNE
  return (u16)r;
}
__device__ __forceinline__ u16 f2h(float f) {
  union { _Float16 h; u16 u; } c; c.h = (_Float16)f; return c.u;
}
__device__ __forceinline__ float h2f(u16 u) {
  union { u16 u; _Float16 h; } c; c.u = u; return (float)c.h;
}
__device__ __forceinline__ float sigmf(float x) { return 1.f / (1.f + __expf(-x)); }
__device__ __forceinline__ float tanhfast(float x) {
  float e = __expf(2.f * x); return 1.f - 2.f / (e + 1.f);  // saturates to ±1
}
__device__ __forceinline__ bf16x8 pack8(const float* p) {
  float4 a = *(const float4*)(p);
  float4 b = *(const float4*)(p + 4);
  bf16x8 fr;
  fr[0] = (short)f2bf(a.x); fr[1] = (short)f2bf(a.y);
  fr[2] = (short)f2bf(a.z); fr[3] = (short)f2bf(a.w);
  fr[4] = (short)f2bf(b.x); fr[5] = (short)f2bf(b.y);
  fr[6] = (short)f2bf(b.z); fr[7] = (short)f2bf(b.w);
  return fr;
}

// ---------------------------------------------------------------------------
// xg GEMM: xg[dir][m][n] = sum_k A[m][k] * W[dir][n][k] + bias[dir][n]
// A: [8192, K] (fp32 if AF32 else bf16) row-major; W: [1536, K] fp32 row-major.
// out: fp16 [8192,1536]. 128x128 tile, BK=32, 4 waves (2x2), 4x4 16x16x32 MFMA.
// (unchanged — ~90 µs/dispatch, not the bottleneck)
// ---------------------------------------------------------------------------
template <int AF32>
__launch_bounds__(256)
__global__ void gemm_xg(const void* __restrict__ Av,
                        const float* __restrict__ W0, const float* __restrict__ W1,
                        const float* __restrict__ b0, const float* __restrict__ b1,
                        u16* __restrict__ xg0, u16* __restrict__ xg1, int K) {
  const int dir = blockIdx.z;
  const float* W = dir ? W1 : W0;
  const float* bias = dir ? b1 : b0;
  u16* xg = dir ? xg1 : xg0;
  const int bm = blockIdx.x, bn = blockIdx.y;
  const int tid = threadIdx.x, lane = tid & 63, wv = tid >> 6;
  const int wm = wv & 1, wn = wv >> 1, quad = lane >> 4, l15 = lane & 15;

  __shared__ u16 As[128 * 40];  // +8 pad per 32-elem row -> conflict-free b128 reads
  __shared__ u16 Bs[128 * 40];

  f32x4 acc[4][4] = {};
  const float* Wb = W + (size_t)(bn * 128) * K;

  for (int k0 = 0; k0 < K; k0 += 32) {
    __syncthreads();  // protect LDS from previous iter's readers
    if constexpr (AF32) {
      const float* Ab = (const float*)Av + (size_t)(bm * 128) * K;
#pragma unroll
      for (int it = 0; it < 4; ++it) {
        int c = tid + it * 256;  // 1024 float4 chunks
        int row = c >> 3, kp = (c & 7) * 4;
        float4 v = *(const float4*)(Ab + (size_t)row * K + k0 + kp);
        ushort4 s = { f2bf(v.x), f2bf(v.y), f2bf(v.z), f2bf(v.w) };
        *(ushort4*)(&As[row * 40 + kp]) = s;
      }
    } else {
      const u16* Ab = (const u16*)Av + (size_t)(bm * 128) * K;
#pragma unroll
      for (int it = 0; it < 2; ++it) {
        int c = tid + it * 256;  // 512 chunks of 8 bf16
        int row = c >> 2, kp = (c & 3) * 8;
        *(bf16x8*)(&As[row * 40 + kp]) = *(const bf16x8*)(Ab + (size_t)row * K + k0 + kp);
      }
    }
#pragma unroll
    for (int it = 0; it < 4; ++it) {  // W is always fp32
      int c = tid + it * 256;
      int row = c >> 3, kp = (c & 7) * 4;
      float4 v = *(const float4*)(Wb + (size_t)row * K + k0 + kp);
      ushort4 s = { f2bf(v.x), f2bf(v.y), f2bf(v.z), f2bf(v.w) };
      *(ushort4*)(&Bs[row * 40 + kp]) = s;
    }
    __syncthreads();
    bf16x8 af[4], bfv[4];
#pragma unroll
    for (int i = 0; i < 4; ++i) {
      af[i] = *(const bf16x8*)(&As[(wm * 64 + i * 16 + l15) * 40 + quad * 8]);
      bfv[i] = *(const bf16x8*)(&Bs[(wn * 64 + i * 16 + l15) * 40 + quad * 8]);
    }
#pragma unroll
    for (int mi = 0; mi < 4; ++mi)
#pragma unroll
      for (int ni = 0; ni < 4; ++ni)
        acc[mi][ni] = __builtin_amdgcn_mfma_f32_16x16x32_bf16(af[mi], bfv[ni], acc[mi][ni], 0, 0, 0);
  }

  // epilogue: + bias, store fp16
#pragma unroll
  for (int ni = 0; ni < 4; ++ni) {
    int n = bn * 128 + wn * 64 + ni * 16 + l15;
    float bv = bias[n];
#pragma unroll
    for (int mi = 0; mi < 4; ++mi) {
      int m0 = bm * 128 + wm * 64 + mi * 16 + quad * 4;
#pragma unroll
      for (int r = 0; r < 4; ++r)
        xg[(size_t)(m0 + r) * 1536 + n] = f2h(acc[mi][ni][r] + bv);
    }
  }
}

// ---------------------------------------------------------------------------
// Persistent GRU recurrence, v3b: lane-local gates (v2) + single-poller rally (v1).
// Identical to v3 except the poll loop keeps s_sleep(1) — the sleepless spin is
// the only hang-capable construct and the only untested delta vs v1/v2's
// proven rallies (round-2 container failure).
// Grid: (4 WGs per direction) x (ndir), 512 threads (8 waves), 1 WG/CU.
// WG w owns hidden cols [w*128, w*128+128); wave wv owns the 16-col quad for
// ALL THREE gates => MFMA D frag (m=batch, n=col) makes the combine lane-local
// (no glds, zero LDS bank conflicts — verified by v2 counters).
// whh: r,z gate B-frags register/AGPR-resident; n-gate frags in wave-private LDS.
// SYNC: only wave 0 polls the 32 per-wave flags and executes ONE agent acquire
// fence per WG per step; __syncthreads() releases all 8 waves, whose plain h
// loads share one freshly-invalidated L1 => ONE 16KB LLC fetch per WG per step
// (v2's per-wave fences caused 8 staggered invalidates that destroyed each
// other's h lines — that was the regression). Producers release per-WAVE flags
// (drains only that wave's stores; no RMW serialization). Output stores are
// issued AFTER the release (off the critical path).
// Parity safety: a wave's h reads at step t precede (release = vmcnt drain)
// its flag t+2; a WG writes parity P of step t+1 only after all 32 flags
// >= t+2, so no buffer still being read is overwritten.
// ---------------------------------------------------------------------------
__launch_bounds__(512, 2)
__global__ void gru_rec(const u16* __restrict__ xg_f, const u16* __restrict__ xg_b,
                        const float* __restrict__ whh_f, const float* __restrict__ whh_b,
                        const float* __restrict__ bhh_f, const float* __restrict__ bhh_b,
                        const float* __restrict__ h0_f, const float* __restrict__ h0_b,
                        void* __restrict__ outp, int out_stride, int out_f32,
                        u16* __restrict__ hbuf, int* __restrict__ counters, int Tn) {
  const int dir = blockIdx.y;
  const u16* xg   = dir ? xg_b  : xg_f;
  const float* whh = dir ? whh_b : whh_f;
  const float* bhh = dir ? bhh_b : bhh_f;
  const float* h0  = dir ? h0_b  : h0_f;
  const int w = blockIdx.x;                      // 0..3
  const int tid = threadIdx.x, lane = tid & 63, wv = tid >> 6;  // wv 0..7
  const int quad = lane >> 4, l15 = lane & 15;
  const int gcol = w * 128 + wv * 16 + l15;      // hidden unit this lane owns
  int* flg = counters + dir * 1024;              // 32 per-wave flags
  u16* hb0 = hbuf + (dir * 2 + 0) * (16 * 512);
  u16* hb1 = hbuf + (dir * 2 + 1) * (16 * 512);
  const int dir_off = dir * 512;

  __shared__ u16 nlds[8 * 8192];                 // 128 KB: per-wave n-gate whh frags

  // --- whh B-frags: rows g*512+gcol, k = kt*32 + quad*8 + j (HW layout m89/m120) ---
  bf16x8 bfr[2][16];
  {
    const float* wr = whh + (size_t)(0 * 512 + gcol) * 512 + quad * 8;
    const float* wz = whh + (size_t)(1 * 512 + gcol) * 512 + quad * 8;
    const float* wn = whh + (size_t)(2 * 512 + gcol) * 512 + quad * 8;
#pragma unroll
    for (int kt = 0; kt < 16; ++kt) {
      bfr[0][kt] = pack8(wr + kt * 32);
      bfr[1][kt] = pack8(wz + kt * 32);
      *(bf16x8*)(&nlds[wv * 8192 + kt * 512 + lane * 8]) = pack8(wn + kt * 32);  // wave-private
    }
  }
  const float bh0 = bhh[0 * 512 + gcol];
  const float bh1 = bhh[1 * 512 + gcol];
  const float bh2 = bhh[2 * 512 + gcol];

  // --- init h: fp32 regs (exact carry) + publish bf16 h0 slice to hb1 ---
  float hv[4];
#pragma unroll
  for (int r = 0; r < 4; ++r) hv[r] = h0[(quad * 4 + r) * 512 + gcol];
#pragma unroll
  for (int r = 0; r < 4; ++r) {
    u32 hb = (u32)f2bf(hv[r]);
    u32 pb = (u32)__shfl_xor((int)hb, 1, 64);
    if (!(lane & 1))
      __hip_atomic_store((u32*)(hb1 + (quad * 4 + r) * 512 + gcol), hb | (pb << 16),
                         __ATOMIC_RELAXED, __HIP_MEMORY_SCOPE_AGENT);
  }
  if (lane == 0)
    __hip_atomic_store(&flg[w * 8 + wv], 1, __ATOMIC_RELEASE, __HIP_MEMORY_SCOPE_AGENT);

  for (int t = 0; t < Tn; ++t) {
    const int te = dir ? (Tn - 1 - t) : t;

    // (a) xg slice for this lane's 4 batch rows -> 12 regs (completes under poll)
    u16 xv[12];
    {
      const u16* xb = xg + (size_t)te * 1536 + gcol;
#pragma unroll
      for (int r = 0; r < 4; ++r)
#pragma unroll
        for (int g = 0; g < 3; ++g)
          xv[r * 3 + g] = xb[(size_t)(quad * 4 + r) * Tn * 1536 + g * 512];
    }

    // (b) wave0 polls all 32 producer flags, ONE acquire fence, barrier rally
    if (wv == 0) {
      const int target = t + 1;
      while (1) {
        int v = (lane < 32)
            ? __hip_atomic_load(&flg[lane], __ATOMIC_RELAXED, __HIP_MEMORY_SCOPE_AGENT)
            : 0x7fffffff;
        if (__all(v >= target)) break;
        __builtin_amdgcn_s_sleep(1);  // proven spin form (v1/v2); avoids mem-system livelock
      }
      __builtin_amdgcn_fence(__ATOMIC_ACQUIRE, "agent");  // one L1/L2 inv per WG per step
    }
    __syncthreads();

    // (c) A-frags: full 16x512 bf16 h from exchange buffer (one LLC fetch, L1-shared)
    const u16* hp = ((t & 1) ? hb0 : hb1) + l15 * 512 + quad * 8;
    bf16x8 afr[16];
#pragma unroll
    for (int kt = 0; kt < 16; ++kt) afr[kt] = *(const bf16x8*)(hp + kt * 32);

    // (d) MFMA: three independent 16-deep chains (r,z from regs; n from LDS)
    f32x4 accr = {0.f, 0.f, 0.f, 0.f}, accz = accr, accn = accr;
#pragma unroll
    for (int kt = 0; kt < 16; ++kt) {
      bf16x8 nf = *(const bf16x8*)(&nlds[wv * 8192 + kt * 512 + lane * 8]);
      accr = __builtin_amdgcn_mfma_f32_16x16x32_bf16(afr[kt], bfr[0][kt], accr, 0, 0, 0);
      accz = __builtin_amdgcn_mfma_f32_16x16x32_bf16(afr[kt], bfr[1][kt], accz, 0, 0, 0);
      accn = __builtin_amdgcn_mfma_f32_16x16x32_bf16(afr[kt], nf, accn, 0, 0, 0);
    }

    // (e) lane-local gate combine + fp32 h update
#pragma unroll
    for (int r = 0; r < 4; ++r) {
      float xr = h2f(xv[r * 3 + 0]);
      float xz = h2f(xv[r * 3 + 1]);
      float xn = h2f(xv[r * 3 + 2]);
      float rg = sigmf(xr + accr[r] + bh0);
      float zg = sigmf(xz + accz[r] + bh1);
      float ng = tanhfast(xn + rg * (accn[r] + bh2));
      hv[r] = (1.f - zg) * ng + zg * hv[r];
    }

    // (f) publish bf16 h (packed pairs via shfl; agent-scope stores)
    u16* hbw = (t & 1) ? hb1 : hb0;
    u32 opk[4];
#pragma unroll
    for (int r = 0; r < 4; ++r) {
      u32 hb = (u32)f2bf(hv[r]);
      u32 pb = (u32)__shfl_xor((int)hb, 1, 64);
      opk[r] = hb | (pb << 16);
      if (!(lane & 1))
        __hip_atomic_store((u32*)(hbw + (quad * 4 + r) * 512 + gcol), opk[r],
                           __ATOMIC_RELAXED, __HIP_MEMORY_SCOPE_AGENT);
    }
    // (g) release: wave-level flag (drains only this wave's memory ops)
    if (lane == 0)
      __hip_atomic_store(&flg[w * 8 + wv], t + 2, __ATOMIC_RELEASE, __HIP_MEMORY_SCOPE_AGENT);

    // (h) sequence output — AFTER the release, off the critical path
    if (out_f32) {
#pragma unroll
      for (int r = 0; r < 4; ++r) {
        float pf = __shfl_xor(hv[r], 1, 64);
        if (!(lane & 1)) {
          float2 o = { hv[r], pf };
          *(float2*)((float*)outp + (size_t)((quad * 4 + r) * Tn + te) * out_stride + dir_off + gcol) = o;
        }
      }
    } else {
#pragma unroll
      for (int r = 0; r < 4; ++r)
        if (!(lane & 1))
          *(u32*)((u16*)outp + (size_t)((quad * 4 + r) * Tn + te) * out_stride + dir_off + gcol) = opk[r];
    }
  }
}

// ---------------------------------------------------------------------------
// Final FC: d_out[b] = sigmoid(out2[b, T-1, :] . fc_w + fc_b)   (all fp32)
// ---------------------------------------------------------------------------
__global__ void fc_kernel(const float* __restrict__ out2, const float* __restrict__ fc_w,
                          const float* __restrict__ fc_b, float* __restrict__ dst) {
  int b = blockIdx.x, lane = threadIdx.x;  // 64 threads
  const float* row = out2 + ((size_t)b * T_SEQ + (T_SEQ - 1)) * HID;
  float s = 0.f;
  for (int j = lane; j < HID; j += 64) s += row[j] * fc_w[j];
#pragma unroll
  for (int off = 32; off > 0; off >>= 1) s += __shfl_down(s, off, 64);
  if (lane == 0) dst[b] = sigmf(s + fc_b[0]);
}

// ---------------------------------------------------------------------------
// inputs (fp32): 0 x, 1 h1, 2 h2, [3..6]=l0f(wih,whh,bih,bhh), [7..10]=l0b,
// [11..14]=l1f, [15..18]=l1b, [19..22]=l2f, [23..26]=l2b, [27..30]=g2, 31 fc_w, 32 fc_b
// d_out (fp32): 16 sigmoid logits, then out2 [16,512,512].
// ws: xg0 fp16 (8192*1536) | xg1 fp16 | outb bf16 (8192*1024) | hbuf bf16 (4*8192)
//     | counters (8192 int)
// ---------------------------------------------------------------------------
extern "C" void kernel_launch(void* const* d_in, const int* in_sizes, int n_in,
                              void* d_out, int out_size, void* d_ws, size_t ws_size,
                              hipStream_t stream) {
  const float* x  = (const float*)d_in[0];
  const float* h1 = (const float*)d_in[1];
  const float* h2 = (const float*)d_in[2];
  auto P = [&](int i) { return (const float*)d_in[i]; };

  u16* xg0 = (u16*)d_ws;
  u16* xg1 = xg0 + (size_t)8192 * 1536;
  u16* outb = xg1 + (size_t)8192 * 1536;
  u16* hbuf = outb + (size_t)8192 * 1024;
  int* counters = (int*)(hbuf + 4 * 8192);
  float* out_f = (float*)d_out;
  float* out2 = out_f + 16;

  hipMemsetAsync(counters, 0, 8192 * sizeof(int), stream);

  // layer 0 (A = x fp32, K=2048)
  gemm_xg<1><<<dim3(64, 12, 2), 256, 0, stream>>>(x, P(3), P(7), P(5), P(9), xg0, xg1, 2048);
  gru_rec<<<dim3(4, 2), 512, 0, stream>>>(xg0, xg1, P(4), P(8), P(6), P(10),
                                          h1, h1 + 8192, outb, 1024, 0, hbuf, counters, T_SEQ);
  // layer 1 (A = outb bf16, K=1024)
  gemm_xg<0><<<dim3(64, 12, 2), 256, 0, stream>>>(outb, P(11), P(15), P(13), P(17), xg0, xg1, 1024);
  gru_rec<<<dim3(4, 2), 512, 0, stream>>>(xg0, xg1, P(12), P(16), P(14), P(18),
                                          h1 + 2 * 8192, h1 + 3 * 8192, outb, 1024, 0, hbuf,
                                          counters + 2048, T_SEQ);
  // layer 2 (K=1024)
  gemm_xg<0><<<dim3(64, 12, 2), 256, 0, stream>>>(outb, P(19), P(23), P(21), P(25), xg0, xg1, 1024);
  gru_rec<<<dim3(4, 2), 512, 0, stream>>>(xg0, xg1, P(20), P(24), P(22), P(26),
                                          h1 + 4 * 8192, h1 + 5 * 8192, outb, 1024, 0, hbuf,
                                          counters + 4096, T_SEQ);
  // g2 (unidirectional, K=1024) -> writes out2 region of d_out (fp32)
  gemm_xg<0><<<dim3(64, 12, 1), 256, 0, stream>>>(outb, P(27), P(27), P(29), P(29), xg0, xg1, 1024);
  gru_rec<<<dim3(4, 1), 512, 0, stream>>>(xg0, xg0, P(28), P(28), P(30), P(30),
                                          h2, h2, out2, 512, 1, hbuf, counters + 6144, T_SEQ);
  fc_kernel<<<16, 64, 0, stream>>>(out2, P(31), P(32), out_f);
}

// Round 4
// 13117.355 us; speedup vs baseline: 1.3959x; 1.1924x over previous
//
#include <hip/hip_runtime.h>
#include <cstdint>
#include <cstddef>

typedef unsigned short u16;
typedef unsigned int u32;
typedef __attribute__((ext_vector_type(8))) short bf16x8;  // 8 bf16 (4 VGPRs) — MFMA A/B frag
typedef __attribute__((ext_vector_type(4))) float f32x4;   // MFMA C/D frag

#define T_SEQ 512
#define HID 512

// ---------- dtype helpers ----------
__device__ __forceinline__ u16 f2bf(float f) {
  union { float f; u32 i; } c; c.f = f;
  u32 r = (c.i + 0x7FFFu + ((c.i >> 16) & 1u)) >> 16;  // RNE
  return (u16)r;
}
__device__ __forceinline__ u16 f2h(float f) {
  union { _Float16 h; u16 u; } c; c.h = (_Float16)f; return c.u;
}
__device__ __forceinline__ float h2f(u16 u) {
  union { u16 u; _Float16 h; } c; c.u = u; return (float)c.h;
}
__device__ __forceinline__ float sigmf(float x) { return 1.f / (1.f + __expf(-x)); }
__device__ __forceinline__ float tanhfast(float x) {
  float e = __expf(2.f * x); return 1.f - 2.f / (e + 1.f);  // saturates to ±1
}
__device__ __forceinline__ bf16x8 pack8(const float* p) {
  float4 a = *(const float4*)(p);
  float4 b = *(const float4*)(p + 4);
  bf16x8 fr;
  fr[0] = (short)f2bf(a.x); fr[1] = (short)f2bf(a.y);
  fr[2] = (short)f2bf(a.z); fr[3] = (short)f2bf(a.w);
  fr[4] = (short)f2bf(b.x); fr[5] = (short)f2bf(b.y);
  fr[6] = (short)f2bf(b.z); fr[7] = (short)f2bf(b.w);
  return fr;
}

// ---------------------------------------------------------------------------
// xg GEMM: xg[dir][m][n] = sum_k A[m][k] * W[dir][n][k] + bias[dir][n]
// A: [8192, K] (fp32 if AF32 else bf16) row-major; W: [1536, K] fp32 row-major.
// out: fp16 [8192,1536]. 128x128 tile, BK=32, 4 waves (2x2), 4x4 16x16x32 MFMA.
// (unchanged — ~90 µs/dispatch, not the bottleneck)
// ---------------------------------------------------------------------------
template <int AF32>
__launch_bounds__(256)
__global__ void gemm_xg(const void* __restrict__ Av,
                        const float* __restrict__ W0, const float* __restrict__ W1,
                        const float* __restrict__ b0, const float* __restrict__ b1,
                        u16* __restrict__ xg0, u16* __restrict__ xg1, int K) {
  const int dir = blockIdx.z;
  const float* W = dir ? W1 : W0;
  const float* bias = dir ? b1 : b0;
  u16* xg = dir ? xg1 : xg0;
  const int bm = blockIdx.x, bn = blockIdx.y;
  const int tid = threadIdx.x, lane = tid & 63, wv = tid >> 6;
  const int wm = wv & 1, wn = wv >> 1, quad = lane >> 4, l15 = lane & 15;

  __shared__ u16 As[128 * 40];  // +8 pad per 32-elem row -> conflict-free b128 reads
  __shared__ u16 Bs[128 * 40];

  f32x4 acc[4][4] = {};
  const float* Wb = W + (size_t)(bn * 128) * K;

  for (int k0 = 0; k0 < K; k0 += 32) {
    __syncthreads();  // protect LDS from previous iter's readers
    if constexpr (AF32) {
      const float* Ab = (const float*)Av + (size_t)(bm * 128) * K;
#pragma unroll
      for (int it = 0; it < 4; ++it) {
        int c = tid + it * 256;  // 1024 float4 chunks
        int row = c >> 3, kp = (c & 7) * 4;
        float4 v = *(const float4*)(Ab + (size_t)row * K + k0 + kp);
        ushort4 s = { f2bf(v.x), f2bf(v.y), f2bf(v.z), f2bf(v.w) };
        *(ushort4*)(&As[row * 40 + kp]) = s;
      }
    } else {
      const u16* Ab = (const u16*)Av + (size_t)(bm * 128) * K;
#pragma unroll
      for (int it = 0; it < 2; ++it) {
        int c = tid + it * 256;  // 512 chunks of 8 bf16
        int row = c >> 2, kp = (c & 3) * 8;
        *(bf16x8*)(&As[row * 40 + kp]) = *(const bf16x8*)(Ab + (size_t)row * K + k0 + kp);
      }
    }
#pragma unroll
    for (int it = 0; it < 4; ++it) {  // W is always fp32
      int c = tid + it * 256;
      int row = c >> 3, kp = (c & 7) * 4;
      float4 v = *(const float4*)(Wb + (size_t)row * K + k0 + kp);
      ushort4 s = { f2bf(v.x), f2bf(v.y), f2bf(v.z), f2bf(v.w) };
      *(ushort4*)(&Bs[row * 40 + kp]) = s;
    }
    __syncthreads();
    bf16x8 af[4], bfv[4];
#pragma unroll
    for (int i = 0; i < 4; ++i) {
      af[i] = *(const bf16x8*)(&As[(wm * 64 + i * 16 + l15) * 40 + quad * 8]);
      bfv[i] = *(const bf16x8*)(&Bs[(wn * 64 + i * 16 + l15) * 40 + quad * 8]);
    }
#pragma unroll
    for (int mi = 0; mi < 4; ++mi)
#pragma unroll
      for (int ni = 0; ni < 4; ++ni)
        acc[mi][ni] = __builtin_amdgcn_mfma_f32_16x16x32_bf16(af[mi], bfv[ni], acc[mi][ni], 0, 0, 0);
  }

  // epilogue: + bias, store fp16
#pragma unroll
  for (int ni = 0; ni < 4; ++ni) {
    int n = bn * 128 + wn * 64 + ni * 16 + l15;
    float bv = bias[n];
#pragma unroll
    for (int mi = 0; mi < 4; ++mi) {
      int m0 = bm * 128 + wm * 64 + mi * 16 + quad * 4;
#pragma unroll
      for (int r = 0; r < 4; ++r)
        xg[(size_t)(m0 + r) * 1536 + n] = f2h(acc[mi][ni][r] + bv);
    }
  }
}

// ---------------------------------------------------------------------------
// Persistent GRU recurrence, v4: v3b with the ARRIVAL path fixed.
// Post-mortem v1 vs v3b: v3b's per-WAVE release flags = 32 agent RELEASE
// stores/dir/step, each emitting s_waitcnt+buffer_wbl2 (dirty-L2 writeback),
// partially serialized in the TCC -> slower than v1's 8 serialized RMW
// arrivals. v4 arrivals: all waves publish h (write-through agent stores),
// ONE __syncthreads (drains every wave's vmcnt), then tid0 does a SINGLE
// plain release store flg[w]=t+2 -> 4 independent non-RMW releases/dir/step
// on 256B-spaced lines. Sequence outputs are write-through agent atomics so
// L2 holds no dirty lines from this kernel (release wbl2 has nothing to do).
// Consumer side unchanged from v3b (proven): wave0 polls the 4 flags, ONE
// acquire fence per WG per step, __syncthreads rally, cached b128 h reads
// shared through freshly-invalidated L1.
// Lane-local gate math unchanged (zero LDS bank conflicts, verified v2/v3b).
// Parity safety: reads of parity P at step t complete before flag t+2 (reads
// precede the pre-release barrier in program order); a WG writes parity P of
// step t+1 only after all flags >= t+2 -> no live buffer overwritten.
// ---------------------------------------------------------------------------
__launch_bounds__(512, 2)
__global__ void gru_rec(const u16* __restrict__ xg_f, const u16* __restrict__ xg_b,
                        const float* __restrict__ whh_f, const float* __restrict__ whh_b,
                        const float* __restrict__ bhh_f, const float* __restrict__ bhh_b,
                        const float* __restrict__ h0_f, const float* __restrict__ h0_b,
                        void* __restrict__ outp, int out_stride, int out_f32,
                        u16* __restrict__ hbuf, int* __restrict__ counters, int Tn) {
  const int dir = blockIdx.y;
  const u16* xg   = dir ? xg_b  : xg_f;
  const float* whh = dir ? whh_b : whh_f;
  const float* bhh = dir ? bhh_b : bhh_f;
  const float* h0  = dir ? h0_b  : h0_f;
  const int w = blockIdx.x;                      // 0..3
  const int tid = threadIdx.x, lane = tid & 63, wv = tid >> 6;  // wv 0..7
  const int quad = lane >> 4, l15 = lane & 15;
  const int gcol = w * 128 + wv * 16 + l15;      // hidden unit this lane owns
  int* flg = counters + dir * 1024;              // 4 per-WG flags, 64-int spaced
  u16* hb0 = hbuf + (dir * 2 + 0) * (16 * 512);
  u16* hb1 = hbuf + (dir * 2 + 1) * (16 * 512);
  const int dir_off = dir * 512;

  __shared__ u16 nlds[8 * 8192];                 // 128 KB: per-wave n-gate whh frags

  // --- whh B-frags: rows g*512+gcol, k = kt*32 + quad*8 + j (HW layout m89/m120) ---
  bf16x8 bfr[2][16];
  {
    const float* wr = whh + (size_t)(0 * 512 + gcol) * 512 + quad * 8;
    const float* wz = whh + (size_t)(1 * 512 + gcol) * 512 + quad * 8;
    const float* wn = whh + (size_t)(2 * 512 + gcol) * 512 + quad * 8;
#pragma unroll
    for (int kt = 0; kt < 16; ++kt) {
      bfr[0][kt] = pack8(wr + kt * 32);
      bfr[1][kt] = pack8(wz + kt * 32);
      *(bf16x8*)(&nlds[wv * 8192 + kt * 512 + lane * 8]) = pack8(wn + kt * 32);  // wave-private
    }
  }
  const float bh0 = bhh[0 * 512 + gcol];
  const float bh1 = bhh[1 * 512 + gcol];
  const float bh2 = bhh[2 * 512 + gcol];

  // --- init h: fp32 regs (exact carry) + publish bf16 h0 slice to hb1 ---
  float hv[4];
#pragma unroll
  for (int r = 0; r < 4; ++r) hv[r] = h0[(quad * 4 + r) * 512 + gcol];
#pragma unroll
  for (int r = 0; r < 4; ++r) {
    u32 hb = (u32)f2bf(hv[r]);
    u32 pb = (u32)__shfl_xor((int)hb, 1, 64);
    if (!(lane & 1))
      __hip_atomic_store((u32*)(hb1 + (quad * 4 + r) * 512 + gcol), hb | (pb << 16),
                         __ATOMIC_RELAXED, __HIP_MEMORY_SCOPE_AGENT);
  }
  __syncthreads();  // drains ALL waves' publish stores (vmcnt 0 before barrier)
  if (tid == 0)
    __hip_atomic_store(&flg[w * 64], 1, __ATOMIC_RELEASE, __HIP_MEMORY_SCOPE_AGENT);

  for (int t = 0; t < Tn; ++t) {
    const int te = dir ? (Tn - 1 - t) : t;

    // (a) xg slice for this lane's 4 batch rows -> 12 regs (completes under poll)
    u16 xv[12];
    {
      const u16* xb = xg + (size_t)te * 1536 + gcol;
#pragma unroll
      for (int r = 0; r < 4; ++r)
#pragma unroll
        for (int g = 0; g < 3; ++g)
          xv[r * 3 + g] = xb[(size_t)(quad * 4 + r) * Tn * 1536 + g * 512];
    }

    // (b) wave0 polls the 4 per-WG flags, ONE acquire fence, barrier rally
    if (wv == 0) {
      const int target = t + 1;
      while (1) {
        int v = (lane < 4)
            ? __hip_atomic_load(&flg[lane * 64], __ATOMIC_RELAXED, __HIP_MEMORY_SCOPE_AGENT)
            : 0x7fffffff;
        if (__all(v >= target)) break;
        __builtin_amdgcn_s_sleep(1);  // proven spin form; avoids mem-system livelock
      }
      __builtin_amdgcn_fence(__ATOMIC_ACQUIRE, "agent");  // one L1/L2 inv per WG per step
    }
    __syncthreads();

    // (c) A-frags: full 16x512 bf16 h from exchange buffer (one LLC fetch, L1-shared)
    const u16* hp = ((t & 1) ? hb0 : hb1) + l15 * 512 + quad * 8;
    bf16x8 afr[16];
#pragma unroll
    for (int kt = 0; kt < 16; ++kt) afr[kt] = *(const bf16x8*)(hp + kt * 32);

    // (d) MFMA: three independent 16-deep chains (r,z from regs; n from LDS)
    f32x4 accr = {0.f, 0.f, 0.f, 0.f}, accz = accr, accn = accr;
#pragma unroll
    for (int kt = 0; kt < 16; ++kt) {
      bf16x8 nf = *(const bf16x8*)(&nlds[wv * 8192 + kt * 512 + lane * 8]);
      accr = __builtin_amdgcn_mfma_f32_16x16x32_bf16(afr[kt], bfr[0][kt], accr, 0, 0, 0);
      accz = __builtin_amdgcn_mfma_f32_16x16x32_bf16(afr[kt], bfr[1][kt], accz, 0, 0, 0);
      accn = __builtin_amdgcn_mfma_f32_16x16x32_bf16(afr[kt], nf, accn, 0, 0, 0);
    }

    // (e) lane-local gate combine + fp32 h update
#pragma unroll
    for (int r = 0; r < 4; ++r) {
      float xr = h2f(xv[r * 3 + 0]);
      float xz = h2f(xv[r * 3 + 1]);
      float xn = h2f(xv[r * 3 + 2]);
      float rg = sigmf(xr + accr[r] + bh0);
      float zg = sigmf(xz + accz[r] + bh1);
      float ng = tanhfast(xn + rg * (accn[r] + bh2));
      hv[r] = (1.f - zg) * ng + zg * hv[r];
    }

    // (f) publish bf16 h (packed pairs via shfl; write-through agent stores)
    u16* hbw = (t & 1) ? hb1 : hb0;
    u32 opk[4];
#pragma unroll
    for (int r = 0; r < 4; ++r) {
      u32 hb = (u32)f2bf(hv[r]);
      u32 pb = (u32)__shfl_xor((int)hb, 1, 64);
      opk[r] = hb | (pb << 16);
      if (!(lane & 1))
        __hip_atomic_store((u32*)(hbw + (quad * 4 + r) * 512 + gcol), opk[r],
                           __ATOMIC_RELAXED, __HIP_MEMORY_SCOPE_AGENT);
    }
    // (g) arrival: one barrier (drains all 8 waves' stores) + ONE release store
    __syncthreads();
    if (tid == 0)
      __hip_atomic_store(&flg[w * 64], t + 2, __ATOMIC_RELEASE, __HIP_MEMORY_SCOPE_AGENT);

    // (h) sequence output — AFTER the release; write-through so L2 stays clean
    if (out_f32) {
#pragma unroll
      for (int r = 0; r < 4; ++r) {
        float pf = __shfl_xor(hv[r], 1, 64);
        if (!(lane & 1)) {
          u32* p = (u32*)((float*)outp + (size_t)((quad * 4 + r) * Tn + te) * out_stride + dir_off + gcol);
          __hip_atomic_store(p + 0, __float_as_uint(hv[r]),
                             __ATOMIC_RELAXED, __HIP_MEMORY_SCOPE_AGENT);
          __hip_atomic_store(p + 1, __float_as_uint(pf),
                             __ATOMIC_RELAXED, __HIP_MEMORY_SCOPE_AGENT);
        }
      }
    } else {
#pragma unroll
      for (int r = 0; r < 4; ++r)
        if (!(lane & 1))
          __hip_atomic_store(
              (u32*)((u16*)outp + (size_t)((quad * 4 + r) * Tn + te) * out_stride + dir_off + gcol),
              opk[r], __ATOMIC_RELAXED, __HIP_MEMORY_SCOPE_AGENT);
    }
  }
}

// ---------------------------------------------------------------------------
// Final FC: d_out[b] = sigmoid(out2[b, T-1, :] . fc_w + fc_b)   (all fp32)
// ---------------------------------------------------------------------------
__global__ void fc_kernel(const float* __restrict__ out2, const float* __restrict__ fc_w,
                          const float* __restrict__ fc_b, float* __restrict__ dst) {
  int b = blockIdx.x, lane = threadIdx.x;  // 64 threads
  const float* row = out2 + ((size_t)b * T_SEQ + (T_SEQ - 1)) * HID;
  float s = 0.f;
  for (int j = lane; j < HID; j += 64) s += row[j] * fc_w[j];
#pragma unroll
  for (int off = 32; off > 0; off >>= 1) s += __shfl_down(s, off, 64);
  if (lane == 0) dst[b] = sigmf(s + fc_b[0]);
}

// ---------------------------------------------------------------------------
// inputs (fp32): 0 x, 1 h1, 2 h2, [3..6]=l0f(wih,whh,bih,bhh), [7..10]=l0b,
// [11..14]=l1f, [15..18]=l1b, [19..22]=l2f, [23..26]=l2b, [27..30]=g2, 31 fc_w, 32 fc_b
// d_out (fp32): 16 sigmoid logits, then out2 [16,512,512].
// ws: xg0 fp16 (8192*1536) | xg1 fp16 | outb bf16 (8192*1024) | hbuf bf16 (4*8192)
//     | counters (8192 int)
// ---------------------------------------------------------------------------
extern "C" void kernel_launch(void* const* d_in, const int* in_sizes, int n_in,
                              void* d_out, int out_size, void* d_ws, size_t ws_size,
                              hipStream_t stream) {
  const float* x  = (const float*)d_in[0];
  const float* h1 = (const float*)d_in[1];
  const float* h2 = (const float*)d_in[2];
  auto P = [&](int i) { return (const float*)d_in[i]; };

  u16* xg0 = (u16*)d_ws;
  u16* xg1 = xg0 + (size_t)8192 * 1536;
  u16* outb = xg1 + (size_t)8192 * 1536;
  u16* hbuf = outb + (size_t)8192 * 1024;
  int* counters = (int*)(hbuf + 4 * 8192);
  float* out_f = (float*)d_out;
  float* out2 = out_f + 16;

  hipMemsetAsync(counters, 0, 8192 * sizeof(int), stream);

  // layer 0 (A = x fp32, K=2048)
  gemm_xg<1><<<dim3(64, 12, 2), 256, 0, stream>>>(x, P(3), P(7), P(5), P(9), xg0, xg1, 2048);
  gru_rec<<<dim3(4, 2), 512, 0, stream>>>(xg0, xg1, P(4), P(8), P(6), P(10),
                                          h1, h1 + 8192, outb, 1024, 0, hbuf, counters, T_SEQ);
  // layer 1 (A = outb bf16, K=1024)
  gemm_xg<0><<<dim3(64, 12, 2), 256, 0, stream>>>(outb, P(11), P(15), P(13), P(17), xg0, xg1, 1024);
  gru_rec<<<dim3(4, 2), 512, 0, stream>>>(xg0, xg1, P(12), P(16), P(14), P(18),
                                          h1 + 2 * 8192, h1 + 3 * 8192, outb, 1024, 0, hbuf,
                                          counters + 2048, T_SEQ);
  // layer 2 (K=1024)
  gemm_xg<0><<<dim3(64, 12, 2), 256, 0, stream>>>(outb, P(19), P(23), P(21), P(25), xg0, xg1, 1024);
  gru_rec<<<dim3(4, 2), 512, 0, stream>>>(xg0, xg1, P(20), P(24), P(22), P(26),
                                          h1 + 4 * 8192, h1 + 5 * 8192, outb, 1024, 0, hbuf,
                                          counters + 4096, T_SEQ);
  // g2 (unidirectional, K=1024) -> writes out2 region of d_out (fp32)
  gemm_xg<0><<<dim3(64, 12, 1), 256, 0, stream>>>(outb, P(27), P(27), P(29), P(29), xg0, xg1, 1024);
  gru_rec<<<dim3(4, 1), 512, 0, stream>>>(xg0, xg0, P(28), P(28), P(30), P(30),
                                          h2, h2, out2, 512, 1, hbuf, counters + 6144, T_SEQ);
  fc_kernel<<<16, 64, 0, stream>>>(out2, P(31), P(32), out_f);
}